// Round 7
// baseline (169.623 us; speedup 1.0000x reference)
//
#include <hip/hip_runtime.h>
#include <hip/hip_bf16.h>

// Problem constants: B=16, N=64, T=128, D=8, N_EMB=64, N_H=128, BN=1024,
// F_in=128, gates=512.

typedef _Float16 half8 __attribute__((ext_vector_type(8)));
typedef _Float16 half4 __attribute__((ext_vector_type(4)));
typedef float f32x4 __attribute__((ext_vector_type(4)));

__device__ __forceinline__ float rcp_(float x){ return __builtin_amdgcn_rcpf(x); }
__device__ __forceinline__ float sigmoidf_(float x){ return rcp_(1.0f + __expf(-x)); }
__device__ __forceinline__ float tanhf_(float x){ return fmaf(-2.0f, rcp_(1.0f + __expf(2.0f*x)), 1.0f); }

// ---------------------------------------------------------------------------
// Kernel 1: repack W_ih (512x128) and W_hh (512x128) into f16 MFMA B-fragment
// order. wfrag[w][i][lane][e], i = src*16 + kk*4 + cti;
//   j = 16*w + 128*cti + (lane&15); k = 32*kk + 8*(lane>>4) + e
// ---------------------------------------------------------------------------
__global__ __launch_bounds__(256) void prep_kernel(const float* __restrict__ W_ih,
                                                   const float* __restrict__ W_hh,
                                                   _Float16* __restrict__ wfrag){
  int gid = blockIdx.x*256 + threadIdx.x;   // [0, 16384)
  int w    = gid >> 11;
  int i    = (gid >> 6) & 31;
  int lane = gid & 63;
  int src = i >> 4, kk = (i >> 2) & 3, cti = i & 3;
  int j = 16*w + 128*cti + (lane & 15);
  int kbase = 32*kk + 8*(lane >> 4);
  const float* W = src ? W_hh : W_ih;
  _Float16* dst = wfrag + (size_t)(((w*32 + i)*64 + lane) * 8);
  #pragma unroll
  for (int e = 0; e < 8; e++) dst[e] = (_Float16)W[j*128 + kbase + e];
}

// ---------------------------------------------------------------------------
// Kernel 2: GCN v2 (unchanged, known-good). One WAVE per (b,t) slice.
// ---------------------------------------------------------------------------
__global__ __launch_bounds__(256) void gcn2_kernel(const float* __restrict__ x,
    const float* __restrict__ Wc, const float* __restrict__ bc,
    const float* __restrict__ Ws, const float* __restrict__ bs,
    _Float16* __restrict__ feat){
  __shared__ _Float16 W2[32*136];
  __shared__ _Float16 As16[4][64*72];
  __shared__ _Float16 zs16[4][64*40];

  int tid = threadIdx.x;
  int wav = tid >> 6, lane = tid & 63;
  int slice = blockIdx.x*4 + wav;       // 0..2047
  int b = slice >> 7, t = slice & 127;
  int c = lane & 15, kq = lane >> 4;

  for (int idx = tid; idx < 32*136; idx += 256){
    int k = idx / 136, f = idx - k*136;
    float v = 0.f;
    if (f < 64){
      if (k < 8) v = Ws[f*8 + k];
      else if (k == 16) v = bs[f];
    } else if (f < 128){
      if (k >= 8 && k < 16) v = Wc[(f-64)*8 + (k-8)];
      else if (k == 16) v = bc[f-64];
    }
    W2[idx] = (_Float16)v;
  }

  _Float16* As_w = &As16[wav][0];
  _Float16* zs_w = &zs16[wav][0];

  const float* xrow = x + ((size_t)(b*64 + lane)*128 + t)*8;
  float4 xlo = *(const float4*)xrow;
  float4 xhi = *(const float4*)(xrow + 4);
  float xr[8] = {xlo.x, xlo.y, xlo.z, xlo.w, xhi.x, xhi.y, xhi.z, xhi.w};
  {
    half8 hx;
    #pragma unroll
    for (int d = 0; d < 8; d++) hx[d] = (_Float16)xr[d];
    half8 h1 = (half8){(_Float16)1.f,0,0,0,0,0,0,0};
    half8 h0 = (half8){0,0,0,0,0,0,0,0};
    *(half8*)(zs_w + lane*40)      = hx;
    *(half8*)(zs_w + lane*40 + 8)  = h1;
    *(half8*)(zs_w + lane*40 + 16) = h1;
    *(half8*)(zs_w + lane*40 + 24) = h0;
  }

  #pragma unroll 4
  for (int m = 0; m < 64; m++){
    float d2 = 0.f;
    #pragma unroll
    for (int d = 0; d < 8; d++){
      float xm = __int_as_float(__builtin_amdgcn_readlane(__float_as_int(xr[d]), m));
      float df = xm - xr[d];
      d2 = fmaf(df, df, d2);
    }
    float wv = (m == lane) ? 0.f : __frsqrt_rn(d2);
    As_w[m*72 + lane] = (_Float16)wv;
  }

  __syncthreads();

  half8 wfr[8];
  #pragma unroll
  for (int nt = 0; nt < 8; nt++){
    half8 tmp;
    #pragma unroll
    for (int e = 0; e < 8; e++) tmp[e] = W2[(8*kq + e)*136 + 16*nt + c];
    wfr[nt] = tmp;
  }

  half8 bx0, bx1;
  {
    half8 t0, t1;
    #pragma unroll
    for (int e = 0; e < 8; e++){
      t0[e] = zs_w[(8*kq + e)*40 + c];
      t1[e] = zs_w[(32 + 8*kq + e)*40 + c];
    }
    bx0 = t0; bx1 = t1;
  }

  const f32x4 zero4 = (f32x4){0.f,0.f,0.f,0.f};

  #pragma unroll
  for (int mt = 0; mt < 4; mt++){
    half8 aa0 = *(const half8*)(As_w + (16*mt + c)*72 + 8*kq);
    half8 aa1 = *(const half8*)(As_w + (16*mt + c)*72 + 32 + 8*kq);
    f32x4 cax = __builtin_amdgcn_mfma_f32_16x16x32_f16(aa0, bx0, zero4, 0,0,0);
    cax = __builtin_amdgcn_mfma_f32_16x16x32_f16(aa1, bx1, cax, 0,0,0);
    int bidx = ((lane & 48) | 8) << 2;
    #pragma unroll
    for (int e = 0; e < 4; e++){
      float rs = __int_as_float(__builtin_amdgcn_ds_bpermute(bidx, __float_as_int(cax[e])));
      float yv = cax[e] * rcp_(fmaxf(rs, 1e-12f));
      if (c < 8) zs_w[(16*mt + 4*kq + e)*40 + 8 + c] = (_Float16)yv;
    }
  }

  _Float16* st = As_w;
  int rr = lane >> 2, qq = lane & 3;
  #pragma unroll
  for (int mt = 0; mt < 4; mt++){
    half8 az = *(const half8*)(zs_w + (16*mt + c)*40 + 8*kq);
    #pragma unroll
    for (int nt = 0; nt < 8; nt++){
      f32x4 pc = __builtin_amdgcn_mfma_f32_16x16x32_f16(az, wfr[nt], zero4, 0,0,0);
      #pragma unroll
      for (int e = 0; e < 4; e++){
        float v = pc[e];
        v = (v > 0.f) ? 1.0507009873554805f*v
                      : 1.7580993408473766f*(__expf(v) - 1.0f);
        st[(4*kq + e)*132 + 16*nt + c] = (_Float16)v;
      }
    }
    asm volatile("s_waitcnt lgkmcnt(0)" ::: "memory");
    size_t obase = ((size_t)t*1024 + (size_t)b*64 + 16*mt + rr)*128 + qq*32;
    #pragma unroll
    for (int j = 0; j < 4; j++){
      half8 pk = *(const half8*)(st + rr*132 + qq*32 + 8*j);
      *(half8*)(feat + obase + 8*j) = pk;
    }
    asm volatile("s_waitcnt lgkmcnt(0)" ::: "memory");
  }
}

// ---------------------------------------------------------------------------
// Kernel 2b: gates_x = feat @ W_ih^T + (b_ih + b_hh), stored f16 as
// gx[t][sample][hh][g] (half4 per (sample,hh)). Block = (t, gq): samples
// 64gq..+63. Wave v owns gate-type v (cols j = 128v + 16ct + c, ct=0..7).
// ---------------------------------------------------------------------------
__global__ __launch_bounds__(256) void xgemm2_kernel(
    const _Float16* __restrict__ wfrag, const _Float16* __restrict__ feat,
    const float* __restrict__ b_ih, const float* __restrict__ b_hh,
    _Float16* __restrict__ gx){
  int blk = blockIdx.x;            // 0..2047
  int t = blk >> 4, gq = blk & 15;
  int tid = threadIdx.x;
  int v = tid >> 6, l = tid & 63;
  int c = l & 15, kq = l >> 4;

  __shared__ _Float16 fs[64*136];     // feat tile, padded rows
  __shared__ _Float16 gxo[16*512];    // one M-tile in [sample][hh][g] order

  #pragma unroll
  for (int i = 0; i < 4; i++){
    int flat = tid + 256*i;           // 0..1023
    int n = flat >> 4, c8 = flat & 15;
    half8 vd = *(const half8*)(feat + ((size_t)t*1024 + 64*gq + n)*128 + c8*8);
    *(half8*)(fs + n*136 + c8*8) = vd;
  }

  // B frags + bias for this wave's 8 col-tiles (gate-type v, hh = 16ct+c)
  half8 bfr[8][4];
  float bb[8];
  #pragma unroll
  for (int ct = 0; ct < 8; ct++){
    #pragma unroll
    for (int kk = 0; kk < 4; kk++)
      bfr[ct][kk] = *(const half8*)(wfrag + (size_t)((ct*32 + kk*4 + v)*64 + l)*8);
    int j = 128*v + 16*ct + c;
    bb[ct] = b_ih[j] + b_hh[j];
  }
  __syncthreads();

  for (int m = 0; m < 4; m++){
    half8 af[4];
    #pragma unroll
    for (int kk = 0; kk < 4; kk++)
      af[kk] = *(const half8*)(fs + (16*m + c)*136 + 32*kk + 8*kq);
    #pragma unroll
    for (int ct = 0; ct < 8; ct++){
      f32x4 acc = (f32x4){bb[ct], bb[ct], bb[ct], bb[ct]};
      #pragma unroll
      for (int kk = 0; kk < 4; kk++)
        acc = __builtin_amdgcn_mfma_f32_16x16x32_f16(af[kk], bfr[ct][kk], acc, 0, 0, 0);
      #pragma unroll
      for (int e = 0; e < 4; e++)
        gxo[(4*kq + e)*512 + (16*ct + c)*4 + v] = (_Float16)acc[e];
    }
    __syncthreads();
    size_t obase = ((size_t)t*1024 + 64*gq + 16*m)*512;
    #pragma unroll
    for (int j = 0; j < 4; j++){
      half8 pk = *(const half8*)(gxo + tid*32 + j*8);
      *(half8*)(gx + obase + tid*32 + j*8) = pk;
    }
    __syncthreads();
  }
}

// ---------------------------------------------------------------------------
// Kernel 3: persistent LSTM v4. 512 blocks x 256 thr (4 waves), 2 samples
// per block -> TWO independent blocks per CU (separate barrier domains) so
// one block's cell-VALU phase overlaps the other's MFMA phase.
// Wave w owns col-tiles ct = w+4m (m=0..7): acc[m] = gate (m>>1) of hidden
// 64*(m&1) + 16w + r. Lane (r,kq): sample kq&1, hidden (kq>>1)*64+16w+r ->
// one cell update per lane. x-gates+bias preloaded from gx (half4, 2 steps
// ahead). One raw s_barrier per step.
// ---------------------------------------------------------------------------
__global__ __launch_bounds__(256, 2) void lstm4_kernel(
    const _Float16* __restrict__ wfrag, const _Float16* __restrict__ gx,
    float* __restrict__ out){
  int tid = threadIdx.x;
  int w = tid >> 6, l = tid & 63;
  int blk = blockIdx.x;            // 0..511
  int r = l & 15, kq = l >> 4;
  __shared__ _Float16 h_lds[2][2*136];   // [parity][sample*136 + hidden]

  // W_hh B-frags for tiles ct = w + 4m: ct -> (w8 = ct&7, cti = ct>>3)
  half8 bf[32];
  #pragma unroll
  for (int m = 0; m < 8; m++){
    int ct = w + 4*m;
    int w8 = ct & 7, cti = ct >> 3;
    #pragma unroll
    for (int kk = 0; kk < 4; kk++)
      bf[m*4 + kk] = *(const half8*)(wfrag + (size_t)((w8*32 + 16 + kk*4 + cti)*64 + l)*8);
  }

  for (int idx = tid; idx < 2*136; idx += 256){
    h_lds[0][idx] = (_Float16)0.f; h_lds[1][idx] = (_Float16)0.f;
  }

  float cc = 0.f;
  const f32x4 zero4 = (f32x4){0.f,0.f,0.f,0.f};

  const int samp = kq & 1, uu = kq >> 1;
  const int hh = uu*64 + 16*w + r;
  const size_t gxbase = ((size_t)(blk*2 + samp)*128 + hh)*4;   // + t*524288
  const int haoff = (r & 1)*136 + 8*kq;                        // + 32*kk
  const int hwoff = samp*136 + hh;

  half4 ga = *(const half4*)(gx + gxbase);               // t = 0
  half4 gb = *(const half4*)(gx + 524288 + gxbase);      // t = 1
  __syncthreads();   // h0 init visible

#define STEP4(T, GU, TL, PR, PW)                                              \
  {                                                                           \
    half4 gcur = GU;                                                          \
    GU = *(const half4*)(gx + (size_t)(TL)*524288 + gxbase);                  \
    half8 ha[4];                                                              \
    _Pragma("unroll")                                                         \
    for (int kk = 0; kk < 4; kk++)                                            \
      ha[kk] = *(const half8*)(&h_lds[PR][haoff + 32*kk]);                    \
    f32x4 acc[8];                                                             \
    _Pragma("unroll")                                                         \
    for (int m = 0; m < 8; m++)                                               \
      acc[m] = __builtin_amdgcn_mfma_f32_16x16x32_f16(ha[0], bf[m*4], zero4, 0,0,0); \
    _Pragma("unroll")                                                         \
    for (int kk = 1; kk < 4; kk++){                                           \
      _Pragma("unroll")                                                       \
      for (int m = 0; m < 8; m++)                                             \
        acc[m] = __builtin_amdgcn_mfma_f32_16x16x32_f16(ha[kk], bf[m*4 + kk], acc[m], 0,0,0); \
    }                                                                         \
    float gv[4];                                                              \
    _Pragma("unroll")                                                         \
    for (int g = 0; g < 4; g++){                                              \
      float vA = samp ? acc[2*g][1]   : acc[2*g][0];                          \
      float vB = samp ? acc[2*g+1][1] : acc[2*g+1][0];                        \
      gv[g] = (uu ? vB : vA) + (float)gcur[g];                                \
    }                                                                         \
    float c_ = fmaf(sigmoidf_(gv[1]), cc, sigmoidf_(gv[0])*tanhf_(gv[2]));    \
    cc = c_;                                                                  \
    float h_ = sigmoidf_(gv[3])*tanhf_(c_);                                   \
    h_lds[PW][hwoff] = (_Float16)h_;                                          \
    asm volatile("s_waitcnt lgkmcnt(0)" ::: "memory");                        \
    __builtin_amdgcn_s_barrier();                                             \
  }

  for (int it = 0; it < 64; ++it){
    int t0 = 2*it, t1 = 2*it + 1;
    int l0 = (t0 + 2 > 127) ? 127 : t0 + 2;
    int l1 = (t1 + 2 > 127) ? 127 : t1 + 2;
    STEP4(t0, ga, l0, 0, 1)
    STEP4(t1, gb, l1, 1, 0)
  }
#undef STEP4

  // t=127 wrote h_lds[0]; lane's own slot holds (sample, hidden) output
  out[((size_t)(blk*2 + samp))*128 + hh] = (float)h_lds[0][hwoff];
}

// ---------------------------------------------------------------------------
extern "C" void kernel_launch(void* const* d_in, const int* in_sizes, int n_in,
                              void* d_out, int out_size, void* d_ws, size_t ws_size,
                              hipStream_t stream) {
  const float* x    = (const float*)d_in[0];
  const float* Wc   = (const float*)d_in[3];
  const float* bc   = (const float*)d_in[4];
  const float* Ws   = (const float*)d_in[5];
  const float* bs   = (const float*)d_in[6];
  const float* W_ih = (const float*)d_in[7];
  const float* W_hh = (const float*)d_in[8];
  const float* b_ih = (const float*)d_in[9];
  const float* b_hh = (const float*)d_in[10];
  float* out = (float*)d_out;

  // ws: [0,256KB) wfrag | [256KB,+33.5MB) feat | [33.8MB,+134MB) gx
  _Float16* wfrag = (_Float16*)d_ws;
  _Float16* feat  = (_Float16*)((char*)d_ws + 262144);
  _Float16* gxbuf = (_Float16*)((char*)d_ws + 33816576);

  prep_kernel<<<64, 256, 0, stream>>>(W_ih, W_hh, wfrag);
  gcn2_kernel<<<512, 256, 0, stream>>>(x, Wc, bc, Ws, bs, feat);
  xgemm2_kernel<<<2048, 256, 0, stream>>>(wfrag, feat, b_ih, b_hh, gxbuf);
  lstm4_kernel<<<512, 256, 0, stream>>>(wfrag, gxbuf, out);
}